// Round 1
// baseline (494.118 us; speedup 1.0000x reference)
//
#include <hip/hip_runtime.h>
#include <math.h>

#define N 16384
#define D 64
#define NCB 16  // candidate slices for KNN

__device__ __forceinline__ float wsum(float v){
  #pragma unroll
  for(int m=32;m>0;m>>=1) v += __shfl_xor(v,m,64);
  return v;
}

// ---- Kernel 1: LN -> x2 -> LN, plus row L2 norms. One wave per row. ----
__global__ __launch_bounds__(256) void ln_kernel(const float* __restrict__ in,
    const float* __restrict__ g1,const float* __restrict__ b1,
    const float* __restrict__ g2,const float* __restrict__ b2,
    float* __restrict__ x, float* __restrict__ xn){
  int wave=threadIdx.x>>6, lane=threadIdx.x&63;
  int row=blockIdx.x*4+wave;
  float v=in[row*64+lane];
  float m=wsum(v)*(1.0f/64.0f);
  float d=v-m;
  float var=wsum(d*d)*(1.0f/64.0f);
  float y=d*(1.0f/sqrtf(var+1e-5f))*g1[lane]+b1[lane];
  y=y+y;  // transformer stubbed as identity + shortcut
  float m2=wsum(y)*(1.0f/64.0f);
  float d2=y-m2;
  float var2=wsum(d2*d2)*(1.0f/64.0f);
  float z=d2*(1.0f/sqrtf(var2+1e-5f))*g2[lane]+b2[lane];
  x[row*64+lane]=z;
  float s=wsum(z*z);
  if(lane==0) xn[row]=fmaxf(sqrtf(s),1e-8f);
}

// ---- Kernel 2: brute-force KNN, partial top-3 per candidate slice. ----
// grid (16 query-blocks, NCB candidate-slices) x 256 threads, 4 queries/thread.
// Distance arithmetic replicates the numpy reference's fp32 rounding exactly:
//   sq  = (c0*c0 + c1*c1) + c2*c2          (plain rounded ops, no FMA contraction)
//   dot = fma(a2,b2, fma(a1,b1, a0*b0))    (BLAS sgemm K-loop with FMA)
//   d   = rn( rn(sq_i + sq_j) - 2*dot )
// Strict '<' insertion while scanning ascending j == stable top-k tie-break.
__global__ __launch_bounds__(256) void knn_partial(const float* __restrict__ coords,
    float* __restrict__ pd, int* __restrict__ pi){
  __shared__ float4 tile[256];
  int tid=threadIdx.x;
  int qb=blockIdx.x, cs=blockIdx.y;
  float qx[4],qy[4],qz[4],qs[4];
  float td0[4],td1[4],td2[4]; int ti0[4],ti1[4],ti2[4];
  int qidx[4];
  #pragma unroll
  for(int qq=0;qq<4;qq++){
    int q=qb*1024+qq*256+tid;
    qidx[qq]=q;
    float a=coords[q*3+0],b=coords[q*3+1],c=coords[q*3+2];
    qx[qq]=a; qy[qq]=b; qz[qq]=c;
    qs[qq]=__fadd_rn(__fadd_rn(__fmul_rn(a,a),__fmul_rn(b,b)),__fmul_rn(c,c));
    td0[qq]=1e30f; td1[qq]=1e30f; td2[qq]=1e30f;
    ti0[qq]=0x7fffffff; ti1[qq]=0x7fffffff; ti2[qq]=0x7fffffff;
  }
  int cbase=cs*1024;
  for(int t=0;t<4;t++){
    int j=cbase+t*256+tid;
    float a=coords[j*3+0],b=coords[j*3+1],c=coords[j*3+2];
    float s=__fadd_rn(__fadd_rn(__fmul_rn(a,a),__fmul_rn(b,b)),__fmul_rn(c,c));
    __syncthreads();
    tile[tid]=make_float4(a,b,c,s);
    __syncthreads();
    for(int jj=0;jj<256;jj++){
      float4 cv=tile[jj];           // same address across lanes -> LDS broadcast
      int j2=cbase+t*256+jj;
      #pragma unroll
      for(int qq=0;qq<4;qq++){
        float dot=__fmaf_rn(qz[qq],cv.z,__fmaf_rn(qy[qq],cv.y,__fmul_rn(qx[qq],cv.x)));
        float dd=__fsub_rn(__fadd_rn(qs[qq],cv.w),__fmul_rn(2.0f,dot));
        if(dd<td2[qq] && j2!=qidx[qq]){
          if(dd<td1[qq]){
            td2[qq]=td1[qq]; ti2[qq]=ti1[qq];
            if(dd<td0[qq]){ td1[qq]=td0[qq]; ti1[qq]=ti0[qq]; td0[qq]=dd; ti0[qq]=j2; }
            else          { td1[qq]=dd; ti1[qq]=j2; }
          } else { td2[qq]=dd; ti2[qq]=j2; }
        }
      }
    }
  }
  #pragma unroll
  for(int qq=0;qq<4;qq++){
    size_t base=((size_t)cs*N+qidx[qq])*3;
    pd[base+0]=td0[qq]; pd[base+1]=td1[qq]; pd[base+2]=td2[qq];
    pi[base+0]=ti0[qq]; pi[base+1]=ti1[qq]; pi[base+2]=ti2[qq];
  }
}

// ---- Kernel 3: merge slice partials -> global top-3 (lexicographic (d,idx)). ----
__global__ __launch_bounds__(256) void knn_merge(const float* __restrict__ pd,
    const int* __restrict__ pi, int* __restrict__ knn){
  int q=blockIdx.x*256+threadIdx.x;
  float D0=1e30f,D1=1e30f,D2=1e30f; int I0=0x7fffffff,I1=0x7fffffff,I2=0x7fffffff;
  for(int s=0;s<NCB;s++){
    size_t base=((size_t)s*N+q)*3;
    #pragma unroll
    for(int m=0;m<3;m++){
      float d=pd[base+m]; int ix=pi[base+m];
      bool lt2=(d<D2)||((d==D2)&&(ix<I2));
      if(lt2){
        bool lt1=(d<D1)||((d==D1)&&(ix<I1));
        if(lt1){
          D2=D1; I2=I1;
          bool lt0=(d<D0)||((d==D0)&&(ix<I0));
          if(lt0){ D1=D0; I1=I0; D0=d; I0=ix; }
          else   { D1=d; I1=ix; }
        } else { D2=d; I2=ix; }
      }
    }
  }
  knn[q*3+0]=I0; knn[q*3+1]=I1; knn[q*3+2]=I2;
}

// ---- Kernel 4: edge weights sigmoid(cos-sim) + dis = 1/sqrt(deg). Wave/node. ----
__global__ __launch_bounds__(256) void ew_kernel(const float* __restrict__ x,
    const float* __restrict__ xn, const int* __restrict__ knn,
    float* __restrict__ ew, float* __restrict__ dis){
  int wave=threadIdx.x>>6, lane=threadIdx.x&63;
  int i=blockIdx.x*4+wave;
  float xi=x[i*64+lane];
  float ni=xn[i];
  float ssum=0.f;
  #pragma unroll
  for(int m=0;m<3;m++){
    int s=knn[i*3+m];
    float xs=x[s*64+lane];
    float dot=wsum(xs*xi);
    float cv=dot/(xn[s]*ni);
    float e=1.f/(1.f+expf(-cv));
    if(lane==0) ew[i*3+m]=e;
    ssum+=e;
  }
  if(lane==0) dis[i]=1.f/sqrtf(ssum+1.0f);  // deg = 1 (self loop) + sum(ew)
}

// ---- Kernel 5/7: H = X * W (16384x64 @ 64x64 fp32, vector ALU). ----
// W staged in LDS; wave handles 4 rows (uniform addr -> scalarized X loads),
// each LDS W read amortized over 4 FMAs.
__global__ __launch_bounds__(256) void gemm64(const float* __restrict__ X,
    const float* __restrict__ W, float* __restrict__ H){
  __shared__ float Ws[4096];
  int tid=threadIdx.x;
  for(int k=tid;k<4096;k+=256) Ws[k]=W[k];
  __syncthreads();
  int wave=tid>>6, lane=tid&63;
  int r0=(blockIdx.x*4+wave)*4;
  const float4* X4=(const float4*)X;
  float acc[4]={0.f,0.f,0.f,0.f};
  #pragma unroll
  for(int k4=0;k4<16;k4++){
    float w0=Ws[(k4*4+0)*64+lane];
    float w1=Ws[(k4*4+1)*64+lane];
    float w2=Ws[(k4*4+2)*64+lane];
    float w3=Ws[(k4*4+3)*64+lane];
    #pragma unroll
    for(int rr=0;rr<4;rr++){
      float4 xv=X4[(r0+rr)*16+k4];
      acc[rr]=fmaf(xv.x,w0,acc[rr]);
      acc[rr]=fmaf(xv.y,w1,acc[rr]);
      acc[rr]=fmaf(xv.z,w2,acc[rr]);
      acc[rr]=fmaf(xv.w,w3,acc[rr]);
    }
  }
  #pragma unroll
  for(int rr=0;rr<4;rr++) H[(r0+rr)*64+lane]=acc[rr];
}

// ---- Kernel 6: GCN aggregate (gather: 3 nbrs + self) + bias + LN + ReLU. ----
__global__ __launch_bounds__(256) void agg1_kernel(const float* __restrict__ h,
    const float* __restrict__ ew, const float* __restrict__ dis, const int* __restrict__ knn,
    const float* __restrict__ bias, const float* __restrict__ gg, const float* __restrict__ gb,
    float* __restrict__ out){
  int wave=threadIdx.x>>6, lane=threadIdx.x&63;
  int i=blockIdx.x*4+wave;
  float di=dis[i];
  float acc=h[i*64+lane]*(di*di);           // self loop, ew=1
  #pragma unroll
  for(int m=0;m<3;m++){
    int s=knn[i*3+m];
    acc+=h[s*64+lane]*(dis[s]*ew[i*3+m]*di);
  }
  acc+=bias[lane];
  float mu=wsum(acc)*(1.0f/64.0f);
  float dd=acc-mu;
  float var=wsum(dd*dd)*(1.0f/64.0f);
  float y=dd*(1.0f/sqrtf(var+1e-5f))*gg[lane]+gb[lane];
  out[i*64+lane]=fmaxf(y,0.0f);
}

// ---- Kernel 8: second GCN aggregate + bias + residual (out = 2x + gcn2). ----
__global__ __launch_bounds__(256) void agg2_kernel(const float* __restrict__ h,
    const float* __restrict__ ew, const float* __restrict__ dis, const int* __restrict__ knn,
    const float* __restrict__ bias, const float* __restrict__ x,
    float* __restrict__ out){
  int wave=threadIdx.x>>6, lane=threadIdx.x&63;
  int i=blockIdx.x*4+wave;
  float di=dis[i];
  float acc=h[i*64+lane]*(di*di);
  #pragma unroll
  for(int m=0;m<3;m++){
    int s=knn[i*3+m];
    acc+=h[s*64+lane]*(dis[s]*ew[i*3+m]*di);
  }
  acc+=bias[lane];
  float xv=x[i*64+lane];
  out[i*64+lane]=(acc+xv)+xv;  // (gcn2 + x) + shortcut, shortcut == x
}

extern "C" void kernel_launch(void* const* d_in, const int* in_sizes, int n_in,
                              void* d_out, int out_size, void* d_ws, size_t ws_size,
                              hipStream_t stream){
  const float* feat  =(const float*)d_in[0];
  // d_in[1] edge_index_tran, d_in[2] edge_attr_rpe, d_in[3] norm_index: unused by reference
  const float* coords=(const float*)d_in[4];
  const float* g1 =(const float*)d_in[5];
  const float* b1n=(const float*)d_in[6];
  const float* g2 =(const float*)d_in[7];
  const float* b2n=(const float*)d_in[8];
  const float* gg =(const float*)d_in[9];
  const float* gb =(const float*)d_in[10];
  const float* W1 =(const float*)d_in[11];
  const float* bb1=(const float*)d_in[12];
  const float* W2 =(const float*)d_in[13];
  const float* bb2=(const float*)d_in[14];
  float* out=(float*)d_out;

  char* ws=(char*)d_ws;
  size_t o=0;
  float* x  =(float*)(ws+o); o+=(size_t)N*64*4;      // post-LN2 features
  float* h  =(float*)(ws+o); o+=(size_t)N*64*4;      // GEMM output (reused)
  float* a1 =(float*)(ws+o); o+=(size_t)N*64*4;      // activated GCN1 output
  float* xn =(float*)(ws+o); o+=(size_t)N*4;         // row norms of x
  float* ew =(float*)(ws+o); o+=(size_t)N*3*4;       // knn edge weights
  float* dis=(float*)(ws+o); o+=(size_t)N*4;         // 1/sqrt(deg)
  int*   knn=(int*)  (ws+o); o+=(size_t)N*3*4;       // neighbor indices
  float* pd =(float*)(ws+o); o+=(size_t)NCB*N*3*4;   // partial top-3 dists
  int*   pi =(int*)  (ws+o); o+=(size_t)NCB*N*3*4;   // partial top-3 idx
  (void)ws_size; (void)in_sizes; (void)n_in; (void)out_size;

  hipLaunchKernelGGL(ln_kernel,   dim3(N/4),      dim3(256), 0, stream, feat,g1,b1n,g2,b2n,x,xn);
  hipLaunchKernelGGL(knn_partial, dim3(16,NCB),   dim3(256), 0, stream, coords,pd,pi);
  hipLaunchKernelGGL(knn_merge,   dim3(N/256),    dim3(256), 0, stream, pd,pi,knn);
  hipLaunchKernelGGL(ew_kernel,   dim3(N/4),      dim3(256), 0, stream, x,xn,knn,ew,dis);
  hipLaunchKernelGGL(gemm64,      dim3(N/16),     dim3(256), 0, stream, x,W1,h);
  hipLaunchKernelGGL(agg1_kernel, dim3(N/4),      dim3(256), 0, stream, h,ew,dis,knn,bb1,gg,gb,a1);
  hipLaunchKernelGGL(gemm64,      dim3(N/16),     dim3(256), 0, stream, a1,W2,h);
  hipLaunchKernelGGL(agg2_kernel, dim3(N/4),      dim3(256), 0, stream, h,ew,dis,knn,bb2,x,out);
}

// Round 2
// 324.968 us; speedup vs baseline: 1.5205x; 1.5205x over previous
//
#include <hip/hip_runtime.h>
#include <math.h>

#define N 16384
#define D 64
#define NCB 16  // candidate slices for KNN (1024 candidates each)
#define QPT 2   // queries per thread in knn_partial

__device__ __forceinline__ float wsum(float v){
  #pragma unroll
  for(int m=32;m>0;m>>=1) v += __shfl_xor(v,m,64);
  return v;
}

// ---- Kernel 1: LN -> x2 -> LN, plus row L2 norms. One wave per row. ----
__global__ __launch_bounds__(256) void ln_kernel(const float* __restrict__ in,
    const float* __restrict__ g1,const float* __restrict__ b1,
    const float* __restrict__ g2,const float* __restrict__ b2,
    float* __restrict__ x, float* __restrict__ xn){
  int wave=threadIdx.x>>6, lane=threadIdx.x&63;
  int row=blockIdx.x*4+wave;
  float v=in[row*64+lane];
  float m=wsum(v)*(1.0f/64.0f);
  float d=v-m;
  float var=wsum(d*d)*(1.0f/64.0f);
  float y=d*(1.0f/sqrtf(var+1e-5f))*g1[lane]+b1[lane];
  y=y+y;  // transformer stubbed as identity + shortcut
  float m2=wsum(y)*(1.0f/64.0f);
  float d2=y-m2;
  float var2=wsum(d2*d2)*(1.0f/64.0f);
  float z=d2*(1.0f/sqrtf(var2+1e-5f))*g2[lane]+b2[lane];
  x[row*64+lane]=z;
  float s=wsum(z*z);
  if(lane==0) xn[row]=fmaxf(sqrtf(s),1e-8f);
}

// ---- Kernel 2: brute-force KNN, partial top-3 per candidate slice. ----
// grid (32 query-blocks of 512, NCB candidate-slices of 1024) x 256 threads,
// QPT=2 queries/thread. Branchless compare-select top-3 insert (the branchy
// version fired on nearly every iteration wave-wide and serialized).
// Distance arithmetic replicates the numpy reference's fp32 rounding exactly:
//   sq  = (c0*c0 + c1*c1) + c2*c2          (plain rounded ops, no contraction)
//   dot = fma(a2,b2, fma(a1,b1, a0*b0))    (BLAS sgemm K-loop with FMA)
//   d   = rn( rn(sq_i + sq_j) - 2*dot )    (2*dot exact, so fma(-2,dot,sc) == sub)
// Strict '<' insertion while scanning ascending j == stable top-k tie-break.
__global__ __launch_bounds__(256) void knn_partial(const float* __restrict__ coords,
    float* __restrict__ pd, int* __restrict__ pi){
  __shared__ float4 tile[256];
  int tid=threadIdx.x;
  int qb=blockIdx.x, cs=blockIdx.y;
  float qx[QPT],qy[QPT],qz[QPT],qs[QPT];
  float td0[QPT],td1[QPT],td2[QPT]; int ti0[QPT],ti1[QPT],ti2[QPT];
  int qidx[QPT];
  #pragma unroll
  for(int qq=0;qq<QPT;qq++){
    int q=qb*(256*QPT)+qq*256+tid;
    qidx[qq]=q;
    float a=coords[q*3+0],b=coords[q*3+1],c=coords[q*3+2];
    qx[qq]=a; qy[qq]=b; qz[qq]=c;
    qs[qq]=__fadd_rn(__fadd_rn(__fmul_rn(a,a),__fmul_rn(b,b)),__fmul_rn(c,c));
    td0[qq]=1e30f; td1[qq]=1e30f; td2[qq]=1e30f;
    ti0[qq]=0x7fffffff; ti1[qq]=0x7fffffff; ti2[qq]=0x7fffffff;
  }
  int cbase=cs*1024;
  for(int t=0;t<4;t++){
    int j=cbase+t*256+tid;
    float a=coords[j*3+0],b=coords[j*3+1],c=coords[j*3+2];
    float s=__fadd_rn(__fadd_rn(__fmul_rn(a,a),__fmul_rn(b,b)),__fmul_rn(c,c));
    __syncthreads();
    tile[tid]=make_float4(a,b,c,s);
    __syncthreads();
    #pragma unroll 8
    for(int jj=0;jj<256;jj++){
      float4 cv=tile[jj];           // same address across lanes -> LDS broadcast
      int j2=cbase+t*256+jj;
      #pragma unroll
      for(int qq=0;qq<QPT;qq++){
        float dot=__fmaf_rn(qz[qq],cv.z,__fmaf_rn(qy[qq],cv.y,__fmul_rn(qx[qq],cv.x)));
        float sc =__fadd_rn(qs[qq],cv.w);
        float dd =__fmaf_rn(-2.0f,dot,sc);       // == rn(sc - 2*dot)
        dd = (j2==qidx[qq]) ? 1e30f : dd;        // exclude self
        bool c0 = dd<td0[qq];
        bool c1 = dd<td1[qq];
        bool c2 = dd<td2[qq];
        // update order 2 -> 1 -> 0 so RHS reads pre-update values
        td2[qq] = c1?td1[qq]:(c2?dd:td2[qq]);  ti2[qq] = c1?ti1[qq]:(c2?j2:ti2[qq]);
        td1[qq] = c0?td0[qq]:(c1?dd:td1[qq]);  ti1[qq] = c0?ti0[qq]:(c1?j2:ti1[qq]);
        td0[qq] = c0?dd:td0[qq];               ti0[qq] = c0?j2:ti0[qq];
      }
    }
  }
  #pragma unroll
  for(int qq=0;qq<QPT;qq++){
    size_t base=((size_t)cs*N+qidx[qq])*3;
    pd[base+0]=td0[qq]; pd[base+1]=td1[qq]; pd[base+2]=td2[qq];
    pi[base+0]=ti0[qq]; pi[base+1]=ti1[qq]; pi[base+2]=ti2[qq];
  }
}

// ---- Kernel 3: merge slice partials -> global top-3 (lexicographic (d,idx)). ----
__global__ __launch_bounds__(256) void knn_merge(const float* __restrict__ pd,
    const int* __restrict__ pi, int* __restrict__ knn){
  int q=blockIdx.x*256+threadIdx.x;
  float D0=1e30f,D1=1e30f,D2=1e30f; int I0=0x7fffffff,I1=0x7fffffff,I2=0x7fffffff;
  for(int s=0;s<NCB;s++){
    size_t base=((size_t)s*N+q)*3;
    #pragma unroll
    for(int m=0;m<3;m++){
      float d=pd[base+m]; int ix=pi[base+m];
      bool lt2=(d<D2)||((d==D2)&&(ix<I2));
      if(lt2){
        bool lt1=(d<D1)||((d==D1)&&(ix<I1));
        if(lt1){
          D2=D1; I2=I1;
          bool lt0=(d<D0)||((d==D0)&&(ix<I0));
          if(lt0){ D1=D0; I1=I0; D0=d; I0=ix; }
          else   { D1=d; I1=ix; }
        } else { D2=d; I2=ix; }
      }
    }
  }
  knn[q*3+0]=I0; knn[q*3+1]=I1; knn[q*3+2]=I2;
}

// ---- Kernel 4: edge weights sigmoid(cos-sim) + dis = 1/sqrt(deg). Wave/node. ----
__global__ __launch_bounds__(256) void ew_kernel(const float* __restrict__ x,
    const float* __restrict__ xn, const int* __restrict__ knn,
    float* __restrict__ ew, float* __restrict__ dis){
  int wave=threadIdx.x>>6, lane=threadIdx.x&63;
  int i=blockIdx.x*4+wave;
  float xi=x[i*64+lane];
  float ni=xn[i];
  float ssum=0.f;
  #pragma unroll
  for(int m=0;m<3;m++){
    int s=knn[i*3+m];
    float xs=x[s*64+lane];
    float dot=wsum(xs*xi);
    float cv=dot/(xn[s]*ni);
    float e=1.f/(1.f+expf(-cv));
    if(lane==0) ew[i*3+m]=e;
    ssum+=e;
  }
  if(lane==0) dis[i]=1.f/sqrtf(ssum+1.0f);  // deg = 1 (self loop) + sum(ew)
}

// ---- Kernel 5/7: H = X * W (16384x64 @ 64x64 fp32, vector ALU). ----
__global__ __launch_bounds__(256) void gemm64(const float* __restrict__ X,
    const float* __restrict__ W, float* __restrict__ H){
  __shared__ float Ws[4096];
  int tid=threadIdx.x;
  for(int k=tid;k<4096;k+=256) Ws[k]=W[k];
  __syncthreads();
  int wave=tid>>6, lane=tid&63;
  int r0=(blockIdx.x*4+wave)*4;
  const float4* X4=(const float4*)X;
  float acc[4]={0.f,0.f,0.f,0.f};
  #pragma unroll
  for(int k4=0;k4<16;k4++){
    float w0=Ws[(k4*4+0)*64+lane];
    float w1=Ws[(k4*4+1)*64+lane];
    float w2=Ws[(k4*4+2)*64+lane];
    float w3=Ws[(k4*4+3)*64+lane];
    #pragma unroll
    for(int rr=0;rr<4;rr++){
      float4 xv=X4[(r0+rr)*16+k4];
      acc[rr]=fmaf(xv.x,w0,acc[rr]);
      acc[rr]=fmaf(xv.y,w1,acc[rr]);
      acc[rr]=fmaf(xv.z,w2,acc[rr]);
      acc[rr]=fmaf(xv.w,w3,acc[rr]);
    }
  }
  #pragma unroll
  for(int rr=0;rr<4;rr++) H[(r0+rr)*64+lane]=acc[rr];
}

// ---- Kernel 6: GCN aggregate (gather: 3 nbrs + self) + bias + LN + ReLU. ----
__global__ __launch_bounds__(256) void agg1_kernel(const float* __restrict__ h,
    const float* __restrict__ ew, const float* __restrict__ dis, const int* __restrict__ knn,
    const float* __restrict__ bias, const float* __restrict__ gg, const float* __restrict__ gb,
    float* __restrict__ out){
  int wave=threadIdx.x>>6, lane=threadIdx.x&63;
  int i=blockIdx.x*4+wave;
  float di=dis[i];
  float acc=h[i*64+lane]*(di*di);           // self loop, ew=1
  #pragma unroll
  for(int m=0;m<3;m++){
    int s=knn[i*3+m];
    acc+=h[s*64+lane]*(dis[s]*ew[i*3+m]*di);
  }
  acc+=bias[lane];
  float mu=wsum(acc)*(1.0f/64.0f);
  float dd=acc-mu;
  float var=wsum(dd*dd)*(1.0f/64.0f);
  float y=dd*(1.0f/sqrtf(var+1e-5f))*gg[lane]+gb[lane];
  out[i*64+lane]=fmaxf(y,0.0f);
}

// ---- Kernel 8: second GCN aggregate + bias + residual (out = 2x + gcn2). ----
__global__ __launch_bounds__(256) void agg2_kernel(const float* __restrict__ h,
    const float* __restrict__ ew, const float* __restrict__ dis, const int* __restrict__ knn,
    const float* __restrict__ bias, const float* __restrict__ x,
    float* __restrict__ out){
  int wave=threadIdx.x>>6, lane=threadIdx.x&63;
  int i=blockIdx.x*4+wave;
  float di=dis[i];
  float acc=h[i*64+lane]*(di*di);
  #pragma unroll
  for(int m=0;m<3;m++){
    int s=knn[i*3+m];
    acc+=h[s*64+lane]*(dis[s]*ew[i*3+m]*di);
  }
  acc+=bias[lane];
  float xv=x[i*64+lane];
  out[i*64+lane]=(acc+xv)+xv;  // (gcn2 + x) + shortcut, shortcut == x
}

extern "C" void kernel_launch(void* const* d_in, const int* in_sizes, int n_in,
                              void* d_out, int out_size, void* d_ws, size_t ws_size,
                              hipStream_t stream){
  const float* feat  =(const float*)d_in[0];
  // d_in[1] edge_index_tran, d_in[2] edge_attr_rpe, d_in[3] norm_index: unused by reference
  const float* coords=(const float*)d_in[4];
  const float* g1 =(const float*)d_in[5];
  const float* b1n=(const float*)d_in[6];
  const float* g2 =(const float*)d_in[7];
  const float* b2n=(const float*)d_in[8];
  const float* gg =(const float*)d_in[9];
  const float* gb =(const float*)d_in[10];
  const float* W1 =(const float*)d_in[11];
  const float* bb1=(const float*)d_in[12];
  const float* W2 =(const float*)d_in[13];
  const float* bb2=(const float*)d_in[14];
  float* out=(float*)d_out;

  char* ws=(char*)d_ws;
  size_t o=0;
  float* x  =(float*)(ws+o); o+=(size_t)N*64*4;      // post-LN2 features
  float* h  =(float*)(ws+o); o+=(size_t)N*64*4;      // GEMM output (reused)
  float* a1 =(float*)(ws+o); o+=(size_t)N*64*4;      // activated GCN1 output
  float* xn =(float*)(ws+o); o+=(size_t)N*4;         // row norms of x
  float* ew =(float*)(ws+o); o+=(size_t)N*3*4;       // knn edge weights
  float* dis=(float*)(ws+o); o+=(size_t)N*4;         // 1/sqrt(deg)
  int*   knn=(int*)  (ws+o); o+=(size_t)N*3*4;       // neighbor indices
  float* pd =(float*)(ws+o); o+=(size_t)NCB*N*3*4;   // partial top-3 dists
  int*   pi =(int*)  (ws+o); o+=(size_t)NCB*N*3*4;   // partial top-3 idx
  (void)ws_size; (void)in_sizes; (void)n_in; (void)out_size;

  hipLaunchKernelGGL(ln_kernel,   dim3(N/4),      dim3(256), 0, stream, feat,g1,b1n,g2,b2n,x,xn);
  hipLaunchKernelGGL(knn_partial, dim3(32,NCB),   dim3(256), 0, stream, coords,pd,pi);
  hipLaunchKernelGGL(knn_merge,   dim3(N/256),    dim3(256), 0, stream, pd,pi,knn);
  hipLaunchKernelGGL(ew_kernel,   dim3(N/4),      dim3(256), 0, stream, x,xn,knn,ew,dis);
  hipLaunchKernelGGL(gemm64,      dim3(N/16),     dim3(256), 0, stream, x,W1,h);
  hipLaunchKernelGGL(agg1_kernel, dim3(N/4),      dim3(256), 0, stream, h,ew,dis,knn,bb1,gg,gb,a1);
  hipLaunchKernelGGL(gemm64,      dim3(N/16),     dim3(256), 0, stream, a1,W2,h);
  hipLaunchKernelGGL(agg2_kernel, dim3(N/4),      dim3(256), 0, stream, h,ew,dis,knn,bb2,x,out);
}

// Round 3
// 263.054 us; speedup vs baseline: 1.8784x; 1.2354x over previous
//
#include <hip/hip_runtime.h>
#include <math.h>

#define N 16384
#define D 64
#define NCB 32   // candidate slices for KNN (512 candidates each)
#define QPT 2    // queries per thread in knnA/knnB

__device__ __forceinline__ float wsum(float v){
  #pragma unroll
  for(int m=32;m>0;m>>=1) v += __shfl_xor(v,m,64);
  return v;
}

// ---- Kernel 1: LN -> x2 -> LN, plus row L2 norms. One wave per row. ----
__global__ __launch_bounds__(256) void ln_kernel(const float* __restrict__ in,
    const float* __restrict__ g1,const float* __restrict__ b1,
    const float* __restrict__ g2,const float* __restrict__ b2,
    float* __restrict__ x, float* __restrict__ xn){
  int wave=threadIdx.x>>6, lane=threadIdx.x&63;
  int row=blockIdx.x*4+wave;
  float v=in[row*64+lane];
  float m=wsum(v)*(1.0f/64.0f);
  float d=v-m;
  float var=wsum(d*d)*(1.0f/64.0f);
  float y=d*(1.0f/sqrtf(var+1e-5f))*g1[lane]+b1[lane];
  y=y+y;  // transformer stubbed as identity + shortcut
  float m2=wsum(y)*(1.0f/64.0f);
  float d2=y-m2;
  float var2=wsum(d2*d2)*(1.0f/64.0f);
  float z=d2*(1.0f/sqrtf(var2+1e-5f))*g2[lane]+b2[lane];
  x[row*64+lane]=z;
  float s=wsum(z*z);
  if(lane==0) xn[row]=fmaxf(sqrtf(s),1e-8f);
}

// ---- KNN pass A: per-slice top-3 DISTANCES only (no indices). ----
// Insert = med3,med3,min = 3 VALU ops (vs ~13 when tracking indices).
// Distance arithmetic identical to the passing round-2 kernel:
//   sq  = (a*a + b*b) + c*c      dot = fma(z, fma(y, mul(x)))
//   dd  = fma(-2, dot, sq_i+sq_j)   (2*dot exact -> == rn(sc - 2*dot))
__global__ __launch_bounds__(256) void knnA(const float* __restrict__ coords,
    float* __restrict__ pdist){
  __shared__ float4 tile[256];
  int tid=threadIdx.x, qb=blockIdx.x, cs=blockIdx.y;
  float qx[QPT],qy[QPT],qz[QPT],qs[QPT];
  float t0[QPT],t1[QPT],t2[QPT]; int qidx[QPT];
  #pragma unroll
  for(int qq=0;qq<QPT;qq++){
    int q=qb*(256*QPT)+qq*256+tid;
    qidx[qq]=q;
    float a=coords[q*3+0],b=coords[q*3+1],c=coords[q*3+2];
    qx[qq]=a; qy[qq]=b; qz[qq]=c;
    qs[qq]=__fadd_rn(__fadd_rn(__fmul_rn(a,a),__fmul_rn(b,b)),__fmul_rn(c,c));
    t0[qq]=1e30f; t1[qq]=1e30f; t2[qq]=1e30f;
  }
  int cbase=cs*512;
  for(int t=0;t<2;t++){
    int j=cbase+t*256+tid;
    float a=coords[j*3+0],b=coords[j*3+1],c=coords[j*3+2];
    float s=__fadd_rn(__fadd_rn(__fmul_rn(a,a),__fmul_rn(b,b)),__fmul_rn(c,c));
    __syncthreads();
    tile[tid]=make_float4(a,b,c,s);
    __syncthreads();
    #pragma unroll 8
    for(int jj=0;jj<256;jj++){
      float4 cv=tile[jj];           // same address across lanes -> LDS broadcast
      int j2=cbase+t*256+jj;
      #pragma unroll
      for(int qq=0;qq<QPT;qq++){
        float dot=__fmaf_rn(qz[qq],cv.z,__fmaf_rn(qy[qq],cv.y,__fmul_rn(qx[qq],cv.x)));
        float sc =__fadd_rn(qs[qq],cv.w);
        float dd =__fmaf_rn(-2.0f,dot,sc);
        dd = (j2==qidx[qq]) ? 1e30f : dd;      // exclude self
        // sorted insert, 3 ops; t2 uses OLD t1, t1 uses OLD t0
        t2[qq]=__builtin_amdgcn_fmed3f(t1[qq],t2[qq],dd);
        t1[qq]=__builtin_amdgcn_fmed3f(t0[qq],t1[qq],dd);
        t0[qq]=fminf(t0[qq],dd);
      }
    }
  }
  #pragma unroll
  for(int qq=0;qq<QPT;qq++){
    size_t base=((size_t)cs*N+qidx[qq])*3;
    pdist[base+0]=t0[qq]; pdist[base+1]=t1[qq]; pdist[base+2]=t2[qq];
  }
}

// ---- KNN merge: global 3rd-smallest distance per query -> threshold. ----
// Also zeroes the pass-B hit counters (stream-ordered before knnB).
__global__ __launch_bounds__(256) void knnA_merge(const float* __restrict__ pdist,
    float* __restrict__ thr, int* __restrict__ cnt){
  int q=blockIdx.x*256+threadIdx.x;
  float t0=1e30f,t1=1e30f,t2=1e30f;
  for(int s=0;s<NCB;s++){
    size_t base=((size_t)s*N+q)*3;
    #pragma unroll
    for(int m=0;m<3;m++){
      float d=pdist[base+m];
      t2=__builtin_amdgcn_fmed3f(t1,t2,d);
      t1=__builtin_amdgcn_fmed3f(t0,t1,d);
      t0=fminf(t0,d);
    }
  }
  thr[q]=t2; cnt[q]=0;
}

// ---- KNN pass B: recover indices. Hot path = dist(5) + 1 cmp. ----
// Branch fires ~4x/query over the full 16K scan; rare path atomically
// appends (idx, dd) to an 8-slot per-query hit list. Self lands in the
// rare path (dd_self ~ 1e-7 <= thr) and is excluded there.
__global__ __launch_bounds__(256) void knnB(const float* __restrict__ coords,
    const float* __restrict__ thr, int* __restrict__ cnt,
    int* __restrict__ hit_i, float* __restrict__ hit_d){
  __shared__ float4 tile[256];
  int tid=threadIdx.x, qb=blockIdx.x, cs=blockIdx.y;
  float qx[QPT],qy[QPT],qz[QPT],qs[QPT],tq[QPT]; int qidx[QPT];
  #pragma unroll
  for(int qq=0;qq<QPT;qq++){
    int q=qb*(256*QPT)+qq*256+tid;
    qidx[qq]=q;
    float a=coords[q*3+0],b=coords[q*3+1],c=coords[q*3+2];
    qx[qq]=a; qy[qq]=b; qz[qq]=c;
    qs[qq]=__fadd_rn(__fadd_rn(__fmul_rn(a,a),__fmul_rn(b,b)),__fmul_rn(c,c));
    tq[qq]=thr[q];
  }
  int cbase=cs*512;
  for(int t=0;t<2;t++){
    int j=cbase+t*256+tid;
    float a=coords[j*3+0],b=coords[j*3+1],c=coords[j*3+2];
    float s=__fadd_rn(__fadd_rn(__fmul_rn(a,a),__fmul_rn(b,b)),__fmul_rn(c,c));
    __syncthreads();
    tile[tid]=make_float4(a,b,c,s);
    __syncthreads();
    #pragma unroll 4
    for(int jj=0;jj<256;jj++){
      float4 cv=tile[jj];
      int j2=cbase+t*256+jj;
      #pragma unroll
      for(int qq=0;qq<QPT;qq++){
        float dot=__fmaf_rn(qz[qq],cv.z,__fmaf_rn(qy[qq],cv.y,__fmul_rn(qx[qq],cv.x)));
        float sc =__fadd_rn(qs[qq],cv.w);
        float dd =__fmaf_rn(-2.0f,dot,sc);
        if(dd<=tq[qq]){
          if(j2!=qidx[qq]){
            int slot=atomicAdd(&cnt[qidx[qq]],1);
            if(slot<8){ hit_i[qidx[qq]*8+slot]=j2; hit_d[qidx[qq]*8+slot]=dd; }
          }
        }
      }
    }
  }
}

// ---- Kernel: final select (lexicographic (d,idx) over <=8 hits) fused with
//      edge weights sigmoid(cos-sim) + dis = 1/sqrt(deg). Wave/node. ----
__global__ __launch_bounds__(256) void ew_kernel(const float* __restrict__ x,
    const float* __restrict__ xn, const int* __restrict__ cnt,
    const int* __restrict__ hit_i, const float* __restrict__ hit_d,
    int* __restrict__ knn, float* __restrict__ ew, float* __restrict__ dis){
  int wave=threadIdx.x>>6, lane=threadIdx.x&63;
  int i=blockIdx.x*4+wave;
  int c=min(cnt[i],8);                 // wave-uniform -> no divergence
  float D0=1e30f,D1=1e30f,D2=1e30f; int I0=i,I1=i,I2=i;
  for(int m=0;m<c;m++){
    float d=hit_d[i*8+m]; int ix=hit_i[i*8+m];   // same-addr broadcast loads
    bool lt2=(d<D2)||((d==D2)&&(ix<I2));
    if(lt2){
      bool lt1=(d<D1)||((d==D1)&&(ix<I1));
      if(lt1){
        D2=D1; I2=I1;
        bool lt0=(d<D0)||((d==D0)&&(ix<I0));
        if(lt0){ D1=D0; I1=I0; D0=d; I0=ix; }
        else   { D1=d; I1=ix; }
      } else { D2=d; I2=ix; }
    }
  }
  if(lane==0){ knn[i*3+0]=I0; knn[i*3+1]=I1; knn[i*3+2]=I2; }
  int ss0=I0, ss1=I1, ss2=I2;
  float xi=x[i*64+lane];
  float ni=xn[i];
  float ssum=0.f;
  int ss[3]={ss0,ss1,ss2};
  #pragma unroll
  for(int m=0;m<3;m++){
    int s=ss[m];
    float xs=x[s*64+lane];
    float dot=wsum(xs*xi);
    float cv=dot/(xn[s]*ni);
    float e=1.f/(1.f+expf(-cv));
    if(lane==0) ew[i*3+m]=e;
    ssum+=e;
  }
  if(lane==0) dis[i]=1.f/sqrtf(ssum+1.0f);  // deg = 1 (self loop) + sum(ew)
}

// ---- H = X * W (16384x64 @ 64x64 fp32, vector ALU). ----
__global__ __launch_bounds__(256) void gemm64(const float* __restrict__ X,
    const float* __restrict__ W, float* __restrict__ H){
  __shared__ float Ws[4096];
  int tid=threadIdx.x;
  for(int k=tid;k<4096;k+=256) Ws[k]=W[k];
  __syncthreads();
  int wave=tid>>6, lane=tid&63;
  int r0=(blockIdx.x*4+wave)*4;
  const float4* X4=(const float4*)X;
  float acc[4]={0.f,0.f,0.f,0.f};
  #pragma unroll
  for(int k4=0;k4<16;k4++){
    float w0=Ws[(k4*4+0)*64+lane];
    float w1=Ws[(k4*4+1)*64+lane];
    float w2=Ws[(k4*4+2)*64+lane];
    float w3=Ws[(k4*4+3)*64+lane];
    #pragma unroll
    for(int rr=0;rr<4;rr++){
      float4 xv=X4[(r0+rr)*16+k4];
      acc[rr]=fmaf(xv.x,w0,acc[rr]);
      acc[rr]=fmaf(xv.y,w1,acc[rr]);
      acc[rr]=fmaf(xv.z,w2,acc[rr]);
      acc[rr]=fmaf(xv.w,w3,acc[rr]);
    }
  }
  #pragma unroll
  for(int rr=0;rr<4;rr++) H[(r0+rr)*64+lane]=acc[rr];
}

// ---- GCN aggregate (gather: 3 nbrs + self) + bias + LN + ReLU. ----
__global__ __launch_bounds__(256) void agg1_kernel(const float* __restrict__ h,
    const float* __restrict__ ew, const float* __restrict__ dis, const int* __restrict__ knn,
    const float* __restrict__ bias, const float* __restrict__ gg, const float* __restrict__ gb,
    float* __restrict__ out){
  int wave=threadIdx.x>>6, lane=threadIdx.x&63;
  int i=blockIdx.x*4+wave;
  float di=dis[i];
  float acc=h[i*64+lane]*(di*di);           // self loop, ew=1
  #pragma unroll
  for(int m=0;m<3;m++){
    int s=knn[i*3+m];
    acc+=h[s*64+lane]*(dis[s]*ew[i*3+m]*di);
  }
  acc+=bias[lane];
  float mu=wsum(acc)*(1.0f/64.0f);
  float dd=acc-mu;
  float var=wsum(dd*dd)*(1.0f/64.0f);
  float y=dd*(1.0f/sqrtf(var+1e-5f))*gg[lane]+gb[lane];
  out[i*64+lane]=fmaxf(y,0.0f);
}

// ---- Second GCN aggregate + bias + residual (out = 2x + gcn2). ----
__global__ __launch_bounds__(256) void agg2_kernel(const float* __restrict__ h,
    const float* __restrict__ ew, const float* __restrict__ dis, const int* __restrict__ knn,
    const float* __restrict__ bias, const float* __restrict__ x,
    float* __restrict__ out){
  int wave=threadIdx.x>>6, lane=threadIdx.x&63;
  int i=blockIdx.x*4+wave;
  float di=dis[i];
  float acc=h[i*64+lane]*(di*di);
  #pragma unroll
  for(int m=0;m<3;m++){
    int s=knn[i*3+m];
    acc+=h[s*64+lane]*(dis[s]*ew[i*3+m]*di);
  }
  acc+=bias[lane];
  float xv=x[i*64+lane];
  out[i*64+lane]=(acc+xv)+xv;  // (gcn2 + x) + shortcut, shortcut == x
}

extern "C" void kernel_launch(void* const* d_in, const int* in_sizes, int n_in,
                              void* d_out, int out_size, void* d_ws, size_t ws_size,
                              hipStream_t stream){
  const float* feat  =(const float*)d_in[0];
  // d_in[1] edge_index_tran, d_in[2] edge_attr_rpe, d_in[3] norm_index: unused by reference
  const float* coords=(const float*)d_in[4];
  const float* g1 =(const float*)d_in[5];
  const float* b1n=(const float*)d_in[6];
  const float* g2 =(const float*)d_in[7];
  const float* b2n=(const float*)d_in[8];
  const float* gg =(const float*)d_in[9];
  const float* gb =(const float*)d_in[10];
  const float* W1 =(const float*)d_in[11];
  const float* bb1=(const float*)d_in[12];
  const float* W2 =(const float*)d_in[13];
  const float* bb2=(const float*)d_in[14];
  float* out=(float*)d_out;

  char* ws=(char*)d_ws;
  size_t o=0;
  float* x    =(float*)(ws+o); o+=(size_t)N*64*4;      // post-LN2 features
  float* h    =(float*)(ws+o); o+=(size_t)N*64*4;      // GEMM output (reused)
  float* a1   =(float*)(ws+o); o+=(size_t)N*64*4;      // activated GCN1 output
  float* xn   =(float*)(ws+o); o+=(size_t)N*4;         // row norms of x
  float* ew   =(float*)(ws+o); o+=(size_t)N*3*4;       // knn edge weights
  float* dis  =(float*)(ws+o); o+=(size_t)N*4;         // 1/sqrt(deg)
  int*   knn  =(int*)  (ws+o); o+=(size_t)N*3*4;       // neighbor indices
  float* pdist=(float*)(ws+o); o+=(size_t)NCB*N*3*4;   // per-slice top-3 dists
  float* thr  =(float*)(ws+o); o+=(size_t)N*4;         // global 3rd-best dist
  int*   cnt  =(int*)  (ws+o); o+=(size_t)N*4;         // hit counters
  int*   hit_i=(int*)  (ws+o); o+=(size_t)N*8*4;       // hit indices (8 slots)
  float* hit_d=(float*)(ws+o); o+=(size_t)N*8*4;       // hit distances
  (void)ws_size; (void)in_sizes; (void)n_in; (void)out_size;

  hipLaunchKernelGGL(ln_kernel,   dim3(N/4),    dim3(256), 0, stream, feat,g1,b1n,g2,b2n,x,xn);
  hipLaunchKernelGGL(knnA,        dim3(32,NCB), dim3(256), 0, stream, coords,pdist);
  hipLaunchKernelGGL(knnA_merge,  dim3(N/256),  dim3(256), 0, stream, pdist,thr,cnt);
  hipLaunchKernelGGL(knnB,        dim3(32,NCB), dim3(256), 0, stream, coords,thr,cnt,hit_i,hit_d);
  hipLaunchKernelGGL(ew_kernel,   dim3(N/4),    dim3(256), 0, stream, x,xn,cnt,hit_i,hit_d,knn,ew,dis);
  hipLaunchKernelGGL(gemm64,      dim3(N/16),   dim3(256), 0, stream, x,W1,h);
  hipLaunchKernelGGL(agg1_kernel, dim3(N/4),    dim3(256), 0, stream, h,ew,dis,knn,bb1,gg,gb,a1);
  hipLaunchKernelGGL(gemm64,      dim3(N/16),   dim3(256), 0, stream, a1,W2,h);
  hipLaunchKernelGGL(agg2_kernel, dim3(N/4),    dim3(256), 0, stream, h,ew,dis,knn,bb2,x,out);
}